// Round 6
// baseline (531.667 us; speedup 1.0000x reference)
//
#include <hip/hip_runtime.h>
#include <hip/hip_bf16.h>

// Problem constants (from reference)
#define N_NODES 100000
#define N_EDGES 1600000
#define N_RELS  8
#define IN_F    64
#define HID_F   64
#define OUT_F   32
#define NSEG    (N_NODES * N_RELS)      // 800000 (node, rel) segments
#define SCAN_EPB 1024                   // elements per scan block (256 thr x 4)
#define SCAN_NB  ((NSEG + SCAN_EPB - 1) / SCAN_EPB)  // 782

typedef __attribute__((ext_vector_type(8))) short short8;   // 8 bf16 = 4 VGPRs
typedef __attribute__((ext_vector_type(4))) float f32x4;

__device__ __forceinline__ float b2f(unsigned short u) {
    return __uint_as_float(((unsigned)u) << 16);
}
__device__ __forceinline__ unsigned short f2b(float f) {
    unsigned u = __float_as_uint(f);
    u += 0x7FFFu + ((u >> 16) & 1u);      // RNE
    return (unsigned short)(u >> 16);
}

// ---------------------------------------------------------------------------
// 1) Histogram: cnt[dst*8+etype] += 1
// ---------------------------------------------------------------------------
__global__ void k_hist(const int* __restrict__ dst, const int* __restrict__ et,
                       int* __restrict__ cnt) {
    int e = blockIdx.x * blockDim.x + threadIdx.x;
    if (e < N_EDGES) {
        int seg = dst[e] * N_RELS + et[e];
        atomicAdd(&cnt[seg], 1);
    }
}

// ---------------------------------------------------------------------------
// 2) Three-pass exclusive scan over the 800k segment counts
// ---------------------------------------------------------------------------
__global__ void k_scanA(const int* __restrict__ cnt, int* __restrict__ bsums) {
    __shared__ int red[256];
    int t = threadIdx.x;
    int base = blockIdx.x * SCAN_EPB + t * 4;
    int s = 0;
    #pragma unroll
    for (int j = 0; j < 4; ++j) {
        int idx = base + j;
        if (idx < NSEG) s += cnt[idx];
    }
    red[t] = s;
    __syncthreads();
    for (int st = 128; st > 0; st >>= 1) {
        if (t < st) red[t] += red[t + st];
        __syncthreads();
    }
    if (t == 0) bsums[blockIdx.x] = red[0];
}

__global__ void k_scanB(int* __restrict__ bsums) {
    __shared__ int s[1024];
    int t = threadIdx.x;
    int own = (t < SCAN_NB) ? bsums[t] : 0;
    s[t] = own;
    __syncthreads();
    for (int off = 1; off < 1024; off <<= 1) {
        int v = (t >= off) ? s[t - off] : 0;
        __syncthreads();
        s[t] += v;
        __syncthreads();
    }
    if (t < SCAN_NB) bsums[t] = s[t] - own;   // exclusive
}

__global__ void k_scanC(const int* __restrict__ cnt, const int* __restrict__ bsums,
                        int* __restrict__ offs) {
    __shared__ int ts[256];
    int t = threadIdx.x;
    int base = blockIdx.x * SCAN_EPB + t * 4;
    int v[4];
    int local = 0;
    #pragma unroll
    for (int j = 0; j < 4; ++j) {
        int idx = base + j;
        v[j] = (idx < NSEG) ? cnt[idx] : 0;
        local += v[j];
    }
    ts[t] = local;
    __syncthreads();
    for (int off = 1; off < 256; off <<= 1) {
        int x = (t >= off) ? ts[t - off] : 0;
        __syncthreads();
        ts[t] += x;
        __syncthreads();
    }
    int run = bsums[blockIdx.x] + (ts[t] - local);
    #pragma unroll
    for (int j = 0; j < 4; ++j) {
        int idx = base + j;
        if (idx < NSEG) offs[idx] = run;
        run += v[j];
    }
}

// ---------------------------------------------------------------------------
// 3) Scatter edges into seg-sorted order, PACKED: val = src*16 + rel
// ---------------------------------------------------------------------------
__global__ void k_scatter(const int* __restrict__ src, const int* __restrict__ dst,
                          const int* __restrict__ et, const int* __restrict__ offs,
                          int* __restrict__ cursor, int* __restrict__ ssrc) {
    int e = blockIdx.x * blockDim.x + threadIdx.x;
    if (e < N_EDGES) {
        int r = et[e];
        int seg = dst[e] * N_RELS + r;
        int pos = offs[seg] + atomicAdd(&cursor[seg], 1);
        ssrc[pos] = src[e] * 16 + r;
    }
}

// ---------------------------------------------------------------------------
// 3b) Fused prep: bf16 transposed weights (both layers) + x -> bf16
//     idx < 36864           : Wt1b[o][k], k in [0,576), last 64 = root1 rows
//     idx < 36864+18432     : Wt2b
//     else (400k)           : x -> xb, 4 floats per thread
// ---------------------------------------------------------------------------
#define PREP_W1 (576 * 64)
#define PREP_W2 (576 * 32)
#define PREP_CVT (N_NODES * 64 / 4)
__global__ void k_prep(const float* __restrict__ W1, const float* __restrict__ root1,
                       const float* __restrict__ W2, const float* __restrict__ root2,
                       const float* __restrict__ x,
                       ushort* __restrict__ Wt1b, ushort* __restrict__ Wt2b,
                       ushort* __restrict__ xb) {
    int idx = blockIdx.x * 256 + threadIdx.x;
    if (idx < PREP_W1) {
        int o = idx / 576, k = idx - o * 576;
        float v = (k < 512) ? W1[k * 64 + o] : root1[(k - 512) * 64 + o];
        Wt1b[idx] = f2b(v);
    } else if (idx < PREP_W1 + PREP_W2) {
        int j = idx - PREP_W1;
        int o = j / 576, k = j - o * 576;
        float v = (k < 512) ? W2[k * 32 + o] : root2[(k - 512) * 32 + o];
        Wt2b[j] = f2b(v);
    } else {
        int j = idx - PREP_W1 - PREP_W2;
        if (j < PREP_CVT) {
            float4 v = *(const float4*)(x + j * 4);
            ushort4 u;
            u.x = f2b(v.x); u.y = f2b(v.y); u.z = f2b(v.z); u.w = f2b(v.w);
            *(ushort4*)(xb + j * 4) = u;
        }
    }
}

// ---------------------------------------------------------------------------
// 4) Fused layer. Block = 512 threads = 8 waves, 16 nodes.
//    Phase 1: wave w aggregates nodes {2w, 2w+1} INTERLEAVED: both nodes'
//             16-edge groups issue their gathers back-to-back -> 32
//             independent loads in flight per wave (vs 16 serial in R5).
//             Scalar if-tree routing (readlane -> SGPR, ~3 VALU/edge).
//    Phase 2: MFMA 16x16x32 bf16, 8 waves = NT n-tiles x S k-splits.
//    Phase 3: k-split partial C reduce via LDS, bias (+ReLU), store.
// ---------------------------------------------------------------------------
template <int NOUT, bool RELU, typename OutT>
__global__ __launch_bounds__(512) void k_layer(
        const ushort* __restrict__ xb, const int* __restrict__ offs,
        const int* __restrict__ cnt, const int* __restrict__ ssrc,
        const ushort* __restrict__ Wtb, const float* __restrict__ bias,
        OutT* __restrict__ out) {
    constexpr int NT = NOUT / 16;     // n-tiles
    constexpr int S  = 8 / NT;        // k-splits
    __shared__ __align__(16) ushort A_lds[16][584];   // 584 = 576 + 8 pad
    __shared__ f32x4 pc[6][64];                        // k-split partials

    const int tid = threadIdx.x;
    const int w = tid >> 6;
    const int f = tid & 63;
    const int node0 = blockIdx.x * 16;

    // ---- phase-2 wave assignment ----
    const int t = w % NT, q = w / NT;
    constexpr int cbase = 18 / S, crem = 18 % S;
    const int cs = q * cbase + (q < crem ? q : crem);
    const int ce = cs + cbase + (q < crem ? 1 : 0);
    const int n0 = t * 16;
    const ushort* bptr = Wtb + (n0 + (f & 15)) * 576 + ((f >> 4) * 8);
    short8 bcur = *(const short8*)(bptr + cs * 32);   // preload 1st B-frag early

    // ---- phase-1 metadata: lanes 0..15 -> offs/cnt for both nodes' 8 rels --
    int ov = 0, cv = 0;
    if (f < 16) {
        ov = offs[(node0 + w * 2) * N_RELS + f];
        cv = cnt [(node0 + w * 2) * N_RELS + f];
    }
    const int sA0 = __builtin_amdgcn_readlane(ov, 0);
    const int ctA = __builtin_amdgcn_readlane(ov, 7)
                  + __builtin_amdgcn_readlane(cv, 7) - sA0;
    const int sB0 = __builtin_amdgcn_readlane(ov, 8);
    const int ctB = __builtin_amdgcn_readlane(ov, 15)
                  + __builtin_amdgcn_readlane(cv, 15) - sB0;

    // root rows: issue early (independent)
    const ushort rootA = xb[(size_t)(node0 + w * 2) * 64 + f];
    const ushort rootB = xb[(size_t)(node0 + w * 2 + 1) * 64 + f];

    float aA[8], aB[8];
    #pragma unroll
    for (int r = 0; r < 8; ++r) { aA[r] = 0.0f; aB[r] = 0.0f; }

    const int ctmax = ctA > ctB ? ctA : ctB;
    for (int cb = 0; cb < ctmax; cb += 64) {
        const int nA = ctA - cb;   // may be <= 0
        const int nB = ctB - cb;
        int pkA = 15, pkB = 15;    // pad: rel=15, src=0
        if (f < nA) pkA = ssrc[sA0 + cb + f];
        if (f < nB) pkB = ssrc[sB0 + cb + f];
        int nmax = nA > nB ? nA : nB;
        if (nmax > 64) nmax = 64;
        for (int e = 0; e < nmax; e += 16) {
            int pvA[16], pvB[16];
            float xvA[16], xvB[16];
            #pragma unroll
            for (int i = 0; i < 16; ++i) {
                pvA[i] = __builtin_amdgcn_readlane(pkA, e + i);   // SGPR
                pvB[i] = __builtin_amdgcn_readlane(pkB, e + i);   // SGPR
            }
            #pragma unroll
            for (int i = 0; i < 16; ++i)    // 32 independent gathers in flight
                xvA[i] = b2f(xb[(size_t)(pvA[i] >> 4) * 64 + f]);
            #pragma unroll
            for (int i = 0; i < 16; ++i)
                xvB[i] = b2f(xb[(size_t)(pvB[i] >> 4) * 64 + f]);
            #pragma unroll
            for (int i = 0; i < 16; ++i) {
                const int rl = pvA[i] & 15;                       // scalar
                if (rl < 4) {
                    if (rl < 2) { if (rl == 0) aA[0] += xvA[i]; else aA[1] += xvA[i]; }
                    else        { if (rl == 2) aA[2] += xvA[i]; else aA[3] += xvA[i]; }
                } else if (rl < 8) {
                    if (rl < 6) { if (rl == 4) aA[4] += xvA[i]; else aA[5] += xvA[i]; }
                    else        { if (rl == 6) aA[6] += xvA[i]; else aA[7] += xvA[i]; }
                }   // rl >= 8: pad, drop
            }
            #pragma unroll
            for (int i = 0; i < 16; ++i) {
                const int rl = pvB[i] & 15;                       // scalar
                if (rl < 4) {
                    if (rl < 2) { if (rl == 0) aB[0] += xvB[i]; else aB[1] += xvB[i]; }
                    else        { if (rl == 2) aB[2] += xvB[i]; else aB[3] += xvB[i]; }
                } else if (rl < 8) {
                    if (rl < 6) { if (rl == 4) aB[4] += xvB[i]; else aB[5] += xvB[i]; }
                    else        { if (rl == 6) aB[6] += xvB[i]; else aB[7] += xvB[i]; }
                }
            }
        }
    }

    // normalize + bf16 -> LDS A rows; root rows = own features
    #pragma unroll
    for (int r = 0; r < 8; ++r) {
        int cA = __builtin_amdgcn_readlane(cv, r);
        int cB = __builtin_amdgcn_readlane(cv, 8 + r);
        A_lds[w * 2][r * 64 + f]     = f2b(aA[r] * (1.0f / (float)(cA > 0 ? cA : 1)));
        A_lds[w * 2 + 1][r * 64 + f] = f2b(aB[r] * (1.0f / (float)(cB > 0 ? cB : 1)));
    }
    A_lds[w * 2][512 + f]     = rootA;
    A_lds[w * 2 + 1][512 + f] = rootB;
    __syncthreads();

    // ---- Phase 2: MFMA over this wave's chunks (software-pipelined B) ----
    f32x4 acc = (f32x4){0.0f, 0.0f, 0.0f, 0.0f};
    const ushort* aptr = &A_lds[f & 15][(f >> 4) * 8];
    for (int c = cs; c < ce; ++c) {
        short8 bnext = bcur;
        if (c + 1 < ce) bnext = *(const short8*)(bptr + (c + 1) * 32);
        short8 af = *(const short8*)(aptr + c * 32);
        acc = __builtin_amdgcn_mfma_f32_16x16x32_bf16(af, bcur, acc, 0, 0, 0);
        bcur = bnext;
    }

    // ---- Phase 3: reduce k-splits, bias (+ReLU), store ----
    if (q > 0) pc[w - NT][f] = acc;
    __syncthreads();
    if (q == 0) {
        #pragma unroll
        for (int j = 1; j < S; ++j) {
            f32x4 p = pc[t + NT * (j - 1)][f];
            acc.x += p.x; acc.y += p.y; acc.z += p.z; acc.w += p.w;
        }
        const int col = f & 15;
        const float bs = bias[n0 + col];
        const int mrow = (f >> 4) * 4;   // C/D: row=(lane>>4)*4+reg, col=lane&15
        #pragma unroll
        for (int i = 0; i < 4; ++i) {
            float v = acc[i] + bs;
            if (RELU) v = fmaxf(v, 0.0f);
            size_t oi = (size_t)(node0 + mrow + i) * NOUT + n0 + col;
            if constexpr (sizeof(OutT) == 2) out[oi] = (OutT)f2b(v);
            else                             out[oi] = (OutT)v;
        }
    }
}

// ---------------------------------------------------------------------------
// Launch
// ---------------------------------------------------------------------------
extern "C" void kernel_launch(void* const* d_in, const int* in_sizes, int n_in,
                              void* d_out, int out_size, void* d_ws, size_t ws_size,
                              hipStream_t stream) {
    const float* x     = (const float*)d_in[0];
    const int*   ei    = (const int*)d_in[1];
    const int*   et    = (const int*)d_in[2];
    const float* W1    = (const float*)d_in[3];
    const float* root1 = (const float*)d_in[4];
    const float* b1    = (const float*)d_in[5];
    const float* W2    = (const float*)d_in[6];
    const float* root2 = (const float*)d_in[7];
    const float* b2    = (const float*)d_in[8];
    float* out = (float*)d_out;

    const int* src = ei;            // edge_index[0]
    const int* dst = ei + N_EDGES;  // edge_index[1]

    // Workspace layout (~41.6 MB)
    char* ws = (char*)d_ws;
    int* cnt    = (int*)(ws);                                   // NSEG ints
    int* cursor = (int*)(ws + (size_t)NSEG * 4);                // NSEG ints
    int* offs   = (int*)(ws + (size_t)NSEG * 8);                // NSEG ints
    int* bsums  = (int*)(ws + (size_t)NSEG * 12);               // 1024 ints
    int* ssrc   = (int*)(ws + (size_t)NSEG * 12 + 4096);        // N_EDGES ints
    ushort* xb  = (ushort*)(ws + (size_t)NSEG * 12 + 4096 + (size_t)N_EDGES * 4); // N*64 bf16
    ushort* h1b = (ushort*)((char*)xb + (size_t)N_NODES * 64 * 2);                // N*64 bf16
    // Wt regions reuse cursor (dead after k_scatter, re-zeroed by memset)
    ushort* Wt1b = (ushort*)cursor;                              // 64*576 bf16 (73.7KB)
    ushort* Wt2b = (ushort*)((char*)cursor + 64 * 576 * 2);      // 32*576 bf16

    // zero cnt + cursor (adjacent)
    hipMemsetAsync(ws, 0, (size_t)NSEG * 8, stream);

    int eb = (N_EDGES + 255) / 256;
    k_hist<<<eb, 256, 0, stream>>>(dst, et, cnt);
    k_scanA<<<SCAN_NB, 256, 0, stream>>>(cnt, bsums);
    k_scanB<<<1, 1024, 0, stream>>>(bsums);
    k_scanC<<<SCAN_NB, 256, 0, stream>>>(cnt, bsums, offs);
    k_scatter<<<eb, 256, 0, stream>>>(src, dst, et, offs, cursor, ssrc);

    // cursor dead now; fused prep: bf16 weights (both layers) + x -> bf16
    int prep_n = PREP_W1 + PREP_W2 + PREP_CVT;
    k_prep<<<(prep_n + 255) / 256, 256, 0, stream>>>(W1, root1, W2, root2, x,
                                                     Wt1b, Wt2b, xb);

    // Layer 1: xb -> h1b (bf16, ReLU), NOUT=64
    k_layer<64, true, ushort><<<N_NODES / 16, 512, 0, stream>>>(
        xb, offs, cnt, ssrc, Wt1b, b1, h1b);
    // Layer 2: h1b -> out (fp32), NOUT=32
    k_layer<32, false, float><<<N_NODES / 16, 512, 0, stream>>>(
        h1b, offs, cnt, ssrc, Wt2b, b2, out);
}

// Round 7
// 440.959 us; speedup vs baseline: 1.2057x; 1.2057x over previous
//
#include <hip/hip_runtime.h>
#include <hip/hip_bf16.h>

// Problem constants (from reference)
#define N_NODES 100000
#define N_EDGES 1600000
#define N_RELS  8
#define IN_F    64
#define HID_F   64
#define OUT_F   32
#define NSEG    (N_NODES * N_RELS)      // 800000 (node, rel) segments
#define SCAN_EPB 1024                   // elements per scan block (256 thr x 4)
#define SCAN_NB  ((NSEG + SCAN_EPB - 1) / SCAN_EPB)  // 782

typedef __attribute__((ext_vector_type(8))) short short8;   // 8 bf16 = 4 VGPRs
typedef __attribute__((ext_vector_type(4))) float f32x4;

__device__ __forceinline__ float b2f(unsigned short u) {
    return __uint_as_float(((unsigned)u) << 16);
}
__device__ __forceinline__ unsigned short f2b(float f) {
    unsigned u = __float_as_uint(f);
    u += 0x7FFFu + ((u >> 16) & 1u);      // RNE
    return (unsigned short)(u >> 16);
}

// ---------------------------------------------------------------------------
// 1) Histogram + rank: rank[e] = old count -> scatter needs no atomics
// ---------------------------------------------------------------------------
__global__ void k_hist(const int* __restrict__ dst, const int* __restrict__ et,
                       int* __restrict__ cnt, int* __restrict__ rank) {
    int e = blockIdx.x * blockDim.x + threadIdx.x;
    if (e < N_EDGES) {
        int seg = dst[e] * N_RELS + et[e];
        rank[e] = atomicAdd(&cnt[seg], 1);
    }
}

// ---------------------------------------------------------------------------
// 2a) Scan pass A: per-block sums (1024 elems / block, 256 threads x 4)
// ---------------------------------------------------------------------------
__global__ void k_scanA(const int* __restrict__ cnt, int* __restrict__ bsums) {
    __shared__ int red[256];
    int t = threadIdx.x;
    int base = blockIdx.x * SCAN_EPB + t * 4;
    int s = 0;
    #pragma unroll
    for (int j = 0; j < 4; ++j) {
        int idx = base + j;
        if (idx < NSEG) s += cnt[idx];
    }
    red[t] = s;
    __syncthreads();
    for (int st = 128; st > 0; st >>= 1) {
        if (t < st) red[t] += red[t + st];
        __syncthreads();
    }
    if (t == 0) bsums[blockIdx.x] = red[0];
}

// ---------------------------------------------------------------------------
// 2b) Scan pass C (scanB inlined): block base = sum(bsums[j<blockIdx]),
//     then per-element exclusive offsets = base + local prefix
// ---------------------------------------------------------------------------
__global__ void k_scanC(const int* __restrict__ cnt, const int* __restrict__ bsums,
                        int* __restrict__ offs) {
    __shared__ int red[256];
    __shared__ int ts[256];
    int t = threadIdx.x;

    // inline scanB: reduce bsums[j] for j < blockIdx.x
    int partial = 0;
    #pragma unroll
    for (int jj = 0; jj < 4; ++jj) {
        int j = t + jj * 256;
        if (j < SCAN_NB && j < blockIdx.x) partial += bsums[j];
    }
    red[t] = partial;
    __syncthreads();
    for (int st = 128; st > 0; st >>= 1) {
        if (t < st) red[t] += red[t + st];
        __syncthreads();
    }
    const int base0 = red[0];

    int base = blockIdx.x * SCAN_EPB + t * 4;
    int v[4];
    int local = 0;
    #pragma unroll
    for (int j = 0; j < 4; ++j) {
        int idx = base + j;
        v[j] = (idx < NSEG) ? cnt[idx] : 0;
        local += v[j];
    }
    ts[t] = local;
    __syncthreads();
    for (int off = 1; off < 256; off <<= 1) {
        int x = (t >= off) ? ts[t - off] : 0;
        __syncthreads();
        ts[t] += x;
        __syncthreads();
    }
    int run = base0 + (ts[t] - local);
    #pragma unroll
    for (int j = 0; j < 4; ++j) {
        int idx = base + j;
        if (idx < NSEG) offs[idx] = run;
        run += v[j];
    }
}

// ---------------------------------------------------------------------------
// 3) Fused scatter (atomic-free via rank) + prep (bf16 weights + x->bf16)
//    idx < N_EDGES                : scatter ssrc[offs[seg]+rank] = src*16+rel
//    idx - N_EDGES < W1 range     : Wt1b[o][k] (k<512 from W1, else root1)
//    next W2 range                : Wt2b
//    next                         : x -> xb, 4 floats/thread
// ---------------------------------------------------------------------------
#define PREP_W1 (576 * 64)
#define PREP_W2 (576 * 32)
#define PREP_CVT (N_NODES * 64 / 4)
#define PREP_TOT (PREP_W1 + PREP_W2 + PREP_CVT)
__global__ void k_scat_prep(const int* __restrict__ src, const int* __restrict__ dst,
                            const int* __restrict__ et, const int* __restrict__ offs,
                            const int* __restrict__ rank, int* __restrict__ ssrc,
                            const float* __restrict__ W1, const float* __restrict__ root1,
                            const float* __restrict__ W2, const float* __restrict__ root2,
                            const float* __restrict__ x,
                            ushort* __restrict__ Wt1b, ushort* __restrict__ Wt2b,
                            ushort* __restrict__ xb) {
    int idx = blockIdx.x * 256 + threadIdx.x;
    if (idx < N_EDGES) {
        int r = et[idx];
        int seg = dst[idx] * N_RELS + r;
        ssrc[offs[seg] + rank[idx]] = src[idx] * 16 + r;
    } else {
        int j = idx - N_EDGES;
        if (j < PREP_W1) {
            int o = j / 576, k = j - o * 576;
            float v = (k < 512) ? W1[k * 64 + o] : root1[(k - 512) * 64 + o];
            Wt1b[j] = f2b(v);
        } else if (j < PREP_W1 + PREP_W2) {
            int j2 = j - PREP_W1;
            int o = j2 / 576, k = j2 - o * 576;
            float v = (k < 512) ? W2[k * 32 + o] : root2[(k - 512) * 32 + o];
            Wt2b[j2] = f2b(v);
        } else {
            int j2 = j - PREP_W1 - PREP_W2;
            if (j2 < PREP_CVT) {
                float4 v = *(const float4*)(x + j2 * 4);
                ushort4 u;
                u.x = f2b(v.x); u.y = f2b(v.y); u.z = f2b(v.z); u.w = f2b(v.w);
                *(ushort4*)(xb + j2 * 4) = u;
            }
        }
    }
}

// ---------------------------------------------------------------------------
// 4) Fused layer (R5 structure — known 143 us). Block = 512 thr = 8 waves,
//    16 nodes.
//    Phase 1: wave w aggregates nodes {2w, 2w+1}: 16 readlane broadcasts
//             (SGPR), 16 independent gathers in flight, scalar if-tree
//             routing; bf16 A rows to LDS in MFMA A-layout (k=512..575 =
//             own features for the root term).
//    Phase 2: MFMA 16x16x32 bf16, 8 waves = NT n-tiles x S k-splits.
//    Phase 3: k-split partial C reduce via LDS, bias (+ReLU), store.
//    NOTE: floor here is L2-miss traffic of random row-gathers (~86 MB
//    FETCH @ ~0.7 TB/s), not VALU.
// ---------------------------------------------------------------------------
template <int NOUT, bool RELU, typename OutT>
__global__ __launch_bounds__(512, 4) void k_layer(
        const ushort* __restrict__ xb, const int* __restrict__ offs,
        const int* __restrict__ cnt, const int* __restrict__ ssrc,
        const ushort* __restrict__ Wtb, const float* __restrict__ bias,
        OutT* __restrict__ out) {
    constexpr int NT = NOUT / 16;     // n-tiles
    constexpr int S  = 8 / NT;        // k-splits
    __shared__ __align__(16) ushort A_lds[16][584];   // 584 = 576 + 8 pad
    __shared__ f32x4 pc[6][64];                        // k-split partials

    const int tid = threadIdx.x;
    const int w = tid >> 6;
    const int f = tid & 63;
    const int node0 = blockIdx.x * 16;

    // ---- phase-2 wave assignment ----
    const int t = w % NT, q = w / NT;
    constexpr int cbase = 18 / S, crem = 18 % S;
    const int cs = q * cbase + (q < crem ? q : crem);
    const int ce = cs + cbase + (q < crem ? 1 : 0);
    const int n0 = t * 16;
    const ushort* bptr = Wtb + (n0 + (f & 15)) * 576 + ((f >> 4) * 8);
    short8 bcur = *(const short8*)(bptr + cs * 32);   // preload 1st B-frag early

    // ---- phase-1 metadata: lanes 0..15 -> offs/cnt for both nodes' 8 rels --
    int ov = 0, cv = 0;
    if (f < 16) {
        ov = offs[(node0 + w * 2) * N_RELS + f];
        cv = cnt [(node0 + w * 2) * N_RELS + f];
    }

    for (int nd = 0; nd < 2; ++nd) {
        const int m = w * 2 + nd;
        const int node = node0 + m;
        const int s0 = __builtin_amdgcn_readlane(ov, nd * 8);
        const int ct = __builtin_amdgcn_readlane(ov, nd * 8 + 7)
                     + __builtin_amdgcn_readlane(cv, nd * 8 + 7) - s0;

        float a[8];
        #pragma unroll
        for (int r = 0; r < 8; ++r) a[r] = 0.0f;

        for (int cb = 0; cb < ct; cb += 64) {
            int n = ct - cb;
            if (n > 64) n = 64;
            int pk = 15;                          // pad: rel=15, src=0
            if (f < n) pk = ssrc[s0 + cb + f];
            for (int e = 0; e < n; e += 16) {
                int pv[16];
                float xv[16];
                #pragma unroll
                for (int i = 0; i < 16; ++i)
                    pv[i] = __builtin_amdgcn_readlane(pk, e + i);   // SGPR
                #pragma unroll
                for (int i = 0; i < 16; ++i)
                    xv[i] = b2f(xb[(size_t)(pv[i] >> 4) * 64 + f]); // 16 indep gathers
                #pragma unroll
                for (int i = 0; i < 16; ++i) {
                    const int rl = pv[i] & 15;                      // scalar
                    if (rl < 4) {
                        if (rl < 2) { if (rl == 0) a[0] += xv[i]; else a[1] += xv[i]; }
                        else        { if (rl == 2) a[2] += xv[i]; else a[3] += xv[i]; }
                    } else if (rl < 8) {
                        if (rl < 6) { if (rl == 4) a[4] += xv[i]; else a[5] += xv[i]; }
                        else        { if (rl == 6) a[6] += xv[i]; else a[7] += xv[i]; }
                    }   // rl >= 8: pad, drop
                }
            }
        }

        // normalize + bf16 -> LDS A rows; root row = own features
        #pragma unroll
        for (int r = 0; r < 8; ++r) {
            int c = __builtin_amdgcn_readlane(cv, nd * 8 + r);
            float inv = 1.0f / (float)(c > 0 ? c : 1);
            A_lds[m][r * 64 + f] = f2b(a[r] * inv);
        }
        A_lds[m][512 + f] = xb[node * 64 + f];
    }
    __syncthreads();

    // ---- Phase 2: MFMA over this wave's chunks (software-pipelined B) ----
    f32x4 acc = (f32x4){0.0f, 0.0f, 0.0f, 0.0f};
    const ushort* aptr = &A_lds[f & 15][(f >> 4) * 8];
    for (int c = cs; c < ce; ++c) {
        short8 bnext = bcur;
        if (c + 1 < ce) bnext = *(const short8*)(bptr + (c + 1) * 32);
        short8 af = *(const short8*)(aptr + c * 32);
        acc = __builtin_amdgcn_mfma_f32_16x16x32_bf16(af, bcur, acc, 0, 0, 0);
        bcur = bnext;
    }

    // ---- Phase 3: reduce k-splits, bias (+ReLU), store ----
    if (q > 0) pc[w - NT][f] = acc;
    __syncthreads();
    if (q == 0) {
        #pragma unroll
        for (int j = 1; j < S; ++j) {
            f32x4 p = pc[t + NT * (j - 1)][f];
            acc.x += p.x; acc.y += p.y; acc.z += p.z; acc.w += p.w;
        }
        const int col = f & 15;
        const float bs = bias[n0 + col];
        const int mrow = (f >> 4) * 4;   // C/D: row=(lane>>4)*4+reg, col=lane&15
        #pragma unroll
        for (int i = 0; i < 4; ++i) {
            float v = acc[i] + bs;
            if (RELU) v = fmaxf(v, 0.0f);
            size_t oi = (size_t)(node0 + mrow + i) * NOUT + n0 + col;
            if constexpr (sizeof(OutT) == 2) out[oi] = (OutT)f2b(v);
            else                             out[oi] = (OutT)v;
        }
    }
}

// ---------------------------------------------------------------------------
// Launch: 7 dispatches (memset, hist, scanA, scanC, scat_prep, layer1, layer2)
// ---------------------------------------------------------------------------
extern "C" void kernel_launch(void* const* d_in, const int* in_sizes, int n_in,
                              void* d_out, int out_size, void* d_ws, size_t ws_size,
                              hipStream_t stream) {
    const float* x     = (const float*)d_in[0];
    const int*   ei    = (const int*)d_in[1];
    const int*   et    = (const int*)d_in[2];
    const float* W1    = (const float*)d_in[3];
    const float* root1 = (const float*)d_in[4];
    const float* b1    = (const float*)d_in[5];
    const float* W2    = (const float*)d_in[6];
    const float* root2 = (const float*)d_in[7];
    const float* b2    = (const float*)d_in[8];
    float* out = (float*)d_out;

    const int* src = ei;            // edge_index[0]
    const int* dst = ei + N_EDGES;  // edge_index[1]

    // Workspace layout (~38.5 MB):
    //   cnt 3.2M | offs 3.2M | bsums 4K | ssrc 6.4M | xb 12.8M |
    //   h1b 12.8M (rank overlaps its first 6.4M — rank dead before h1b
    //   written) | Wt1b 73.7K | Wt2b 36.9K
    char* ws = (char*)d_ws;
    int*    cnt   = (int*)(ws);
    int*    offs  = (int*)(ws + (size_t)NSEG * 4);
    int*    bsums = (int*)(ws + (size_t)NSEG * 8);
    int*    ssrc  = (int*)(ws + (size_t)NSEG * 8 + 4096);
    ushort* xb    = (ushort*)(ws + (size_t)NSEG * 8 + 4096 + (size_t)N_EDGES * 4);
    ushort* h1b   = (ushort*)((char*)xb + (size_t)N_NODES * 64 * 2);
    int*    rank  = (int*)h1b;   // overlap: rank dead after k_scat_prep
    ushort* Wt1b  = (ushort*)((char*)h1b + (size_t)N_NODES * 64 * 2);
    ushort* Wt2b  = (ushort*)((char*)Wt1b + (size_t)PREP_W1 * 2);

    // zero cnt only (rank written unconditionally)
    hipMemsetAsync(cnt, 0, (size_t)NSEG * 4, stream);

    int eb = (N_EDGES + 255) / 256;
    k_hist<<<eb, 256, 0, stream>>>(dst, et, cnt, rank);
    k_scanA<<<SCAN_NB, 256, 0, stream>>>(cnt, bsums);
    k_scanC<<<SCAN_NB, 256, 0, stream>>>(cnt, bsums, offs);

    int spb = (N_EDGES + PREP_TOT + 255) / 256;
    k_scat_prep<<<spb, 256, 0, stream>>>(src, dst, et, offs, rank, ssrc,
                                         W1, root1, W2, root2, x,
                                         Wt1b, Wt2b, xb);

    // Layer 1: xb -> h1b (bf16, ReLU), NOUT=64
    k_layer<64, true, ushort><<<N_NODES / 16, 512, 0, stream>>>(
        xb, offs, cnt, ssrc, Wt1b, b1, h1b);
    // Layer 2: h1b -> out (fp32), NOUT=32
    k_layer<32, false, float><<<N_NODES / 16, 512, 0, stream>>>(
        h1b, offs, cnt, ssrc, Wt2b, b2, out);
}